// Round 2
// baseline (4937.865 us; speedup 1.0000x reference)
//
#include <hip/hip_runtime.h>

typedef __bf16 bf16x8 __attribute__((ext_vector_type(8)));
typedef float f32x4 __attribute__((ext_vector_type(4)));

union UQ { uint4 q; bf16x8 v; };

__device__ __forceinline__ unsigned short f2bf(float x){
  union { float f; unsigned u; } c; c.f = x;
  return (unsigned short)((c.u + 0x7fffu + ((c.u >> 16) & 1u)) >> 16);
}

__global__ void zero_flags(int* __restrict__ p){
  p[blockIdx.x * 256 + threadIdx.x] = 0;
}

// Pack W (512x512 f32 row-major) into canonical MFMA fragment stream:
// dst[(ntile*16 + kt)*64 + lane] = 8 bf16 of W[ntile*16 + (lane&15)][kt*32 + (lane>>4)*8 + j]
// Serves as A-frag (row = ntile-local n) or B-frag (col) — same layout.
__global__ void pack_kernel(const float* __restrict__ W, uint4* __restrict__ dst){
  int tid  = blockIdx.x * 512 + threadIdx.x;   // 0..32767
  int lane = tid & 63;
  int kt   = (tid >> 6) & 15;
  int ntl  = tid >> 10;
  int row  = ntl * 16 + (lane & 15);
  int k0   = kt * 32 + ((lane >> 4) << 3);
  const float* s = &W[row * 512 + k0];
  unsigned a0 = f2bf(s[0]) | ((unsigned)f2bf(s[1]) << 16);
  unsigned a1 = f2bf(s[2]) | ((unsigned)f2bf(s[3]) << 16);
  unsigned a2 = f2bf(s[4]) | ((unsigned)f2bf(s[5]) << 16);
  unsigned a3 = f2bf(s[6]) | ((unsigned)f2bf(s[7]) << 16);
  dst[tid] = (uint4){a0, a1, a2, a3};
}

// h0[b][n] = sum_o init[b][o] * Whi[n][o]; also emit bf16 copy for step-0 A-frags
__global__ void h0_kernel(const float* __restrict__ init, const float* __restrict__ Whi,
                          float* __restrict__ h0, unsigned short* __restrict__ hb0){
  int b = blockIdx.x, n = threadIdx.x;  // 256 x 512
  __shared__ float ic[512];
  ic[n] = init[b * 512 + n];
  __syncthreads();
  const float4* wr = (const float4*)&Whi[n * 512];
  float s = 0.f;
  #pragma unroll 8
  for (int o = 0; o < 128; o++){
    float4 w = wr[o];
    s += w.x * ic[4*o] + w.y * ic[4*o+1] + w.z * ic[4*o+2] + w.w * ic[4*o+3];
  }
  h0[b * 512 + n] = s;
  hb0[b * 512 + n] = f2bf(s);
}

// Recurrence: 64 WGs = 16 batch-groups (m) x 4 col-slices (sl).
// WG(m,sl): batches [16m..16m+16), cols [128sl..128sl+128).
// Wave w holds its 16-col W_rec tile entirely in VGPRs (u[16], 64 regs).
// Per step: A-frags (h) from LLC exchange buffer, MFMA z^T = W*h^T,
// epilogue, write bf16 h-slice to xbuf, release flag; poll peers, acquire,
// next step. Lane owns (b=lane&15, 4 consecutive n) -> 8B xbuf store,
// float4 hidden store.
__global__ __launch_bounds__(512, 2)
void rnn_kernel(const float* __restrict__ inputs, const float* __restrict__ W_in,
                const float* __restrict__ b_in, const float* __restrict__ b_rec,
                const uint4* __restrict__ wfrag, const float* __restrict__ h0,
                const unsigned short* __restrict__ hb0,
                unsigned short* __restrict__ xbuf, int* __restrict__ flags,
                float* __restrict__ hidden){
  const int m   = blockIdx.x & 15, sl = blockIdx.x >> 4;
  const int g16 = m << 4;
  const int tid = threadIdx.x, w = tid >> 6, lane = tid & 63;
  const int col = lane & 15, quad = lane >> 4;
  __shared__ float xin_s[2][32];

  // persistent W_rec fragments for this wave's 16 columns
  UQ u[16];
  #pragma unroll
  for (int kt = 0; kt < 16; kt++)
    u[kt].q = wfrag[((((sl << 3) + w) << 4) + kt) * 64 + lane];

  const int nb = (sl << 7) + (w << 4) + (quad << 2);  // 4 cols nb..nb+3, batch=col
  float win0[4], win1[4], bcv[4];
  #pragma unroll
  for (int r = 0; r < 4; r++){
    win0[r] = W_in[2*(nb+r)];
    win1[r] = W_in[2*(nb+r)+1];
    bcv[r]  = b_in[nb+r] + b_rec[nb+r];
  }

  float h[4];
  {
    float4 h4 = *(const float4*)&h0[(g16 + col) * 512 + nb];
    h[0] = h4.x; h[1] = h4.y; h[2] = h4.z; h[3] = h4.w;
  }

  if (tid < 32) xin_s[0][tid] = inputs[((g16 + (tid >> 1)) * 512 + 0) * 2 + (tid & 1)];
  __syncthreads();

  int* flg = flags + (m << 9);                 // flags[m][t]
  unsigned short* xg = xbuf + (m << 14);       // 2 buffers x 16x512 bf16

  for (int t = 0; t < 512; t++){
    if (t > 0){
      if (tid == 0)
        while (__hip_atomic_load(&flg[t-1], __ATOMIC_RELAXED, __HIP_MEMORY_SCOPE_AGENT) < 4) {}
      __syncthreads();
      __builtin_amdgcn_fence(__ATOMIC_ACQUIRE, "agent");
    }
    const unsigned short* asrc = t ? (xg + (((t - 1) & 1) << 13)) : (hb0 + (g16 << 9));

    // A-frags: h[b=col][kt*32 + quad*8 + j]
    UQ a[16];
    #pragma unroll
    for (int kt = 0; kt < 16; kt++)
      a[kt].q = *(const uint4*)(asrc + (col << 9) + (kt << 5) + (quad << 3));

    f32x4 acc0 = {0.f,0.f,0.f,0.f}, acc1 = {0.f,0.f,0.f,0.f};
    #pragma unroll
    for (int kt = 0; kt < 16; kt += 2){
      acc0 = __builtin_amdgcn_mfma_f32_16x16x32_bf16(u[kt].v,   a[kt].v,   acc0, 0, 0, 0);
      acc1 = __builtin_amdgcn_mfma_f32_16x16x32_bf16(u[kt+1].v, a[kt+1].v, acc1, 0, 0, 0);
    }

    // epilogue: z^T[n][b]; lane: rows nb+r, col b=col
    const float x0 = xin_s[t & 1][2 * col];
    const float x1 = xin_s[t & 1][2 * col + 1];
    unsigned short us[4];
    #pragma unroll
    for (int r = 0; r < 4; r++){
      float z  = (acc0[r] + acc1[r]) + fmaf(x0, win0[r], fmaf(x1, win1[r], bcv[r]));
      float e  = __expf(2.0f * z);
      float th = 1.0f - 2.0f / (e + 1.0f);
      h[r] = 0.9f * h[r] + 0.1f * th;
      us[r] = f2bf(h[r]);
    }
    *(uint2*)(xg + ((t & 1) << 13) + (col << 9) + nb) =
        (uint2){ (unsigned)us[0] | ((unsigned)us[1] << 16),
                 (unsigned)us[2] | ((unsigned)us[3] << 16) };

    __syncthreads();   // all xbuf stores drained to L2 (vmcnt0) by barrier
    if (tid == 0){
      __builtin_amdgcn_fence(__ATOMIC_RELEASE, "agent");   // wbl2: L2 -> LLC
      __hip_atomic_fetch_add(&flg[t], 1, __ATOMIC_RELAXED, __HIP_MEMORY_SCOPE_AGENT);
    }

    // off critical path: x prefetch + hidden output
    if (tid < 32 && t < 511)
      xin_s[(t + 1) & 1][tid] = inputs[((g16 + (tid >> 1)) * 512 + (t + 1)) * 2 + (tid & 1)];
    *(float4*)&hidden[((g16 + col) * 512 + t) * 512 + nb] =
        (float4){h[0], h[1], h[2], h[3]};
  }
}

// outputs = hidden @ W_out^T : 1024 WGs x 8 waves; WG tile 128M x 512N.
__global__ __launch_bounds__(512, 2)
void out_gemm(const float* __restrict__ hidden, const uint4* __restrict__ wofrag,
              float* __restrict__ outp){
  const int tid  = threadIdx.x;
  const int w    = tid >> 6;
  const int lane = tid & 63;
  const int col  = lane & 15;
  const int quad = lane >> 4;
  const int ms   = w >> 1;
  const int nh   = w & 1;
  const int m0   = blockIdx.x << 7;

  __shared__ unsigned short albf[128 * 32];  // swizzled bf16 A-tile

  f32x4 acc[2][16];
  #pragma unroll
  for (int mt = 0; mt < 2; mt++)
    #pragma unroll
    for (int nt = 0; nt < 16; nt++) acc[mt][nt] = (f32x4){0.f, 0.f, 0.f, 0.f};

  for (int kt = 0; kt < 16; kt++){
    #pragma unroll
    for (int i = 0; i < 2; i++){
      int r  = (tid >> 3) + (i << 6);
      int c4 = (tid & 7) << 2;
      float4 v = *(const float4*)&hidden[(m0 + r) * 512 + (kt << 5) + c4];
      unsigned lo = f2bf(v.x) | ((unsigned)f2bf(v.y) << 16);
      unsigned hi = f2bf(v.z) | ((unsigned)f2bf(v.w) << 16);
      int byteoff = (r << 6) + ((c4 << 1) ^ (((r >> 1) & 3) << 4));
      *(uint2*)((char*)albf + byteoff) = (uint2){lo, hi};
    }
    __syncthreads();

    bf16x8 af[2];
    #pragma unroll
    for (int mt = 0; mt < 2; mt++){
      int rl = (ms << 5) + (mt << 4) + col;
      int byteoff = (rl << 6) + ((quad << 4) ^ (((rl >> 1) & 3) << 4));
      af[mt] = *(const bf16x8*)((const char*)albf + byteoff);
    }

    #pragma unroll
    for (int nt = 0; nt < 16; nt++){
      UQ u; u.q = wofrag[((((nh << 4) + nt) << 4) + kt) * 64 + lane];
      acc[0][nt] = __builtin_amdgcn_mfma_f32_16x16x32_bf16(af[0], u.v, acc[0][nt], 0, 0, 0);
      acc[1][nt] = __builtin_amdgcn_mfma_f32_16x16x32_bf16(af[1], u.v, acc[1][nt], 0, 0, 0);
    }
    __syncthreads();
  }

  #pragma unroll
  for (int mt = 0; mt < 2; mt++)
    #pragma unroll
    for (int nt = 0; nt < 16; nt++)
      #pragma unroll
      for (int r = 0; r < 4; r++)
        outp[(m0 + (ms << 5) + (mt << 4) + (quad << 2) + r) * 512
             + (nh << 8) + (nt << 4) + col] = acc[mt][nt][r];
}

extern "C" void kernel_launch(void* const* d_in, const int* in_sizes, int n_in,
                              void* d_out, int out_size, void* d_ws, size_t ws_size,
                              hipStream_t stream){
  const float* inputs  = (const float*)d_in[0];  // (256,512,2)
  const float* initc   = (const float*)d_in[1];  // (256,512)
  const float* W_in    = (const float*)d_in[2];  // (512,2)
  const float* b_in    = (const float*)d_in[3];  // (512)
  const float* W_rec   = (const float*)d_in[4];  // (512,512)
  const float* b_rec   = (const float*)d_in[5];  // (512)
  const float* W_out   = (const float*)d_in[6];  // (512,512)
  const float* W_hi    = (const float*)d_in[7];  // (512,512)

  float* hidden  = (float*)d_out;                 // 256*512*512
  float* outputs = hidden + (size_t)67108864;     // second half

  char* ws = (char*)d_ws;
  uint4*          wrec_f = (uint4*)ws;                        // 512 KB
  uint4*          wout_f = (uint4*)(ws + (512 << 10));        // 512 KB
  float*          h0     = (float*)(ws + (1024 << 10));       // 512 KB
  unsigned short* hb0    = (unsigned short*)(ws + (1536 << 10)); // 256 KB
  unsigned short* xbuf   = (unsigned short*)(ws + (1792 << 10)); // 512 KB (16 groups x 2 x 16KB)
  int*            flags  = (int*)(ws + (2304 << 10));         // 32 KB (16 x 512)

  zero_flags<<<32, 256, 0, stream>>>(flags);
  pack_kernel<<<64, 512, 0, stream>>>(W_rec, wrec_f);
  pack_kernel<<<64, 512, 0, stream>>>(W_out, wout_f);
  h0_kernel<<<256, 512, 0, stream>>>(initc, W_hi, h0, hb0);
  rnn_kernel<<<64, 512, 0, stream>>>(inputs, W_in, b_in, b_rec, wrec_f, h0, hb0,
                                     xbuf, flags, hidden);
  out_gemm<<<1024, 512, 0, stream>>>(hidden, wout_f, outputs);
}

// Round 3
// 1821.871 us; speedup vs baseline: 2.7103x; 2.7103x over previous
//
#include <hip/hip_runtime.h>

typedef __bf16 bf16x8 __attribute__((ext_vector_type(8)));
typedef float f32x4 __attribute__((ext_vector_type(4)));

union UQ { uint4 q; bf16x8 v; };

__device__ __forceinline__ unsigned short f2bf(float x){
  union { float f; unsigned u; } c; c.f = x;
  return (unsigned short)((c.u + 0x7fffu + ((c.u >> 16) & 1u)) >> 16);
}

__global__ void zero_flags(int* __restrict__ p){
  p[blockIdx.x * 256 + threadIdx.x] = 0;
}

// Pack W (512x512 f32 row-major) into canonical MFMA fragment stream:
// dst[(ntile*16 + kt)*64 + lane] = 8 bf16 of W[ntile*16 + (lane&15)][kt*32 + (lane>>4)*8 + j]
__global__ void pack_kernel(const float* __restrict__ W, uint4* __restrict__ dst){
  int tid  = blockIdx.x * 512 + threadIdx.x;   // 0..32767
  int lane = tid & 63;
  int kt   = (tid >> 6) & 15;
  int ntl  = tid >> 10;
  int row  = ntl * 16 + (lane & 15);
  int k0   = kt * 32 + ((lane >> 4) << 3);
  const float* s = &W[row * 512 + k0];
  unsigned a0 = f2bf(s[0]) | ((unsigned)f2bf(s[1]) << 16);
  unsigned a1 = f2bf(s[2]) | ((unsigned)f2bf(s[3]) << 16);
  unsigned a2 = f2bf(s[4]) | ((unsigned)f2bf(s[5]) << 16);
  unsigned a3 = f2bf(s[6]) | ((unsigned)f2bf(s[7]) << 16);
  dst[tid] = (uint4){a0, a1, a2, a3};
}

// h0[b][n] = sum_o init[b][o] * Whi[n][o]; also bf16 copy for step-0 staging
__global__ void h0_kernel(const float* __restrict__ init, const float* __restrict__ Whi,
                          float* __restrict__ h0, unsigned short* __restrict__ hb0){
  int b = blockIdx.x, n = threadIdx.x;  // 256 x 512
  __shared__ float ic[512];
  ic[n] = init[b * 512 + n];
  __syncthreads();
  const float4* wr = (const float4*)&Whi[n * 512];
  float s = 0.f;
  #pragma unroll 8
  for (int o = 0; o < 128; o++){
    float4 w = wr[o];
    s += w.x * ic[4*o] + w.y * ic[4*o+1] + w.z * ic[4*o+2] + w.w * ic[4*o+3];
  }
  h0[b * 512 + n] = s;
  hb0[b * 512 + n] = f2bf(s);
}

// Recurrence: 32 WGs = 16 batch-groups (m) x 2 col-halves (sl).
// WG(m,sl): batches [16m..16m+16), cols [256sl..256sl+256).
// Wave w holds its 32-col W_rec slice in VGPRs (u0[16]+u1[16] = 128 regs).
// Cross-WG h exchange: agent-scope atomicExch (send, ack via vmcnt) +
// relaxed agent atomic flag store; consumer polls peer flag, atomic-loads
// peer half, stages into LDS (own half staged from registers). NO fences.
__global__ __launch_bounds__(512, 2)
void rnn_kernel(const float* __restrict__ inputs, const float* __restrict__ W_in,
                const float* __restrict__ b_in, const float* __restrict__ b_rec,
                const uint4* __restrict__ wfrag, const float* __restrict__ h0,
                const unsigned short* __restrict__ hb0,
                unsigned short* __restrict__ xbuf, int* __restrict__ flags,
                float* __restrict__ hidden){
  const int m    = blockIdx.x & 15, sl = blockIdx.x >> 4;
  const int g16  = m << 4;
  const int tid  = threadIdx.x, w = tid >> 6, lane = tid & 63;
  const int col  = lane & 15, quad = lane >> 4;
  const int nbase = (sl << 8) + (w << 5);    // this wave's 32 cols

  __shared__ unsigned short hbuf[2][16 * 512];  // double-buffered swizzled bf16 h
  __shared__ float xin_s[2][32];

  // persistent W_rec fragments: 2 n-tiles x 16 kt
  UQ u0[16], u1[16];
  {
    const int nt0 = nbase >> 4;
    #pragma unroll
    for (int kt = 0; kt < 16; kt++){
      u0[kt].q = wfrag[((nt0 * 16) + kt) * 64 + lane];
      u1[kt].q = wfrag[(((nt0 + 1) * 16) + kt) * 64 + lane];
    }
  }

  float win0[8], win1[8], bcv[8];
  #pragma unroll
  for (int i = 0; i < 2; i++)
    #pragma unroll
    for (int r = 0; r < 4; r++){
      int n = nbase + i * 16 + (quad << 2) + r;
      win0[i*4+r] = W_in[2*n];  win1[i*4+r] = W_in[2*n+1];
      bcv[i*4+r]  = b_in[n] + b_rec[n];
    }

  float h[8];
  #pragma unroll
  for (int i = 0; i < 2; i++){
    float4 h4 = *(const float4*)&h0[(g16 + col) * 512 + nbase + i * 16 + (quad << 2)];
    h[i*4+0] = h4.x; h[i*4+1] = h4.y; h[i*4+2] = h4.z; h[i*4+3] = h4.w;
  }

  { // step-0 staging: full h0 (bf16) -> LDS slot 0, swizzled
    int b = tid >> 5, n0 = (tid & 31) << 4;
    const uint4* s4 = (const uint4*)&hb0[(g16 + b) * 512 + n0];
    uint4 v0 = s4[0], v1 = s4[1];
    int sw = (b & 7) << 3;
    *(uint4*)&hbuf[0][b * 512 + (n0 ^ sw)]       = v0;
    *(uint4*)&hbuf[0][b * 512 + ((n0 + 8) ^ sw)] = v1;
  }
  if (tid < 32) xin_s[0][tid] = inputs[((g16 + (tid >> 1)) * 512 + 0) * 2 + (tid & 1)];

  // flags[sl][m][t]: producer (m,sl) stores 1; consumer polls peer's
  int* flg_my = flags + ((sl * 16 + m) << 9);
  int* flg_pr = flags + (((1 - sl) * 16 + m) << 9);
  unsigned long long* xm = (unsigned long long*)(xbuf + (m << 14)); // 2 slots x 16 x 512 bf16
  const int prow = tid >> 5;                              // peer-stage batch row
  const int pn0  = ((1 - sl) << 8) + ((tid & 31) << 3);   // peer-stage col start (8 cols)
  unsigned long long own[2] = {0ull, 0ull};

  for (int t = 0; t < 512; t++){
    const int s = t & 1;
    if (t > 0){
      // own half of h_{t-1} from regs -> LDS (before poll: hides LDS latency)
      const int swc = (col & 7) << 3;
      #pragma unroll
      for (int i = 0; i < 2; i++){
        int n = nbase + i * 16 + (quad << 2);
        *(unsigned long long*)&hbuf[s][col * 512 + (n ^ swc)] = own[i];
      }
      // wait for peer's step t-1 publication
      while (__hip_atomic_load(&flg_pr[t - 1], __ATOMIC_RELAXED, __HIP_MEMORY_SCOPE_AGENT) == 0) {}
      // fetch peer half from LLC (coherent loads, no inv needed)
      unsigned long long p0 = __hip_atomic_load(&xm[(s << 11) + (prow << 7) + (pn0 >> 2)],
                                                __ATOMIC_RELAXED, __HIP_MEMORY_SCOPE_AGENT);
      unsigned long long p1 = __hip_atomic_load(&xm[(s << 11) + (prow << 7) + (pn0 >> 2) + 1],
                                                __ATOMIC_RELAXED, __HIP_MEMORY_SCOPE_AGENT);
      const int swb = (prow & 7) << 3;
      union { unsigned long long d; uint2 u; } c0, c1;
      c0.d = p0; c1.d = p1;
      *(uint4*)&hbuf[s][prow * 512 + (pn0 ^ swb)] = (uint4){c0.u.x, c0.u.y, c1.u.x, c1.u.y};
    }
    __syncthreads();   // S2: staging visible to all waves

    if (t < 511 && tid < 32)
      xin_s[(t + 1) & 1][tid] = inputs[((g16 + (tid >> 1)) * 512 + (t + 1)) * 2 + (tid & 1)];

    f32x4 acc0 = {0.f,0.f,0.f,0.f}, acc1 = {0.f,0.f,0.f,0.f};
    #pragma unroll
    for (int kt = 0; kt < 16; kt++){
      UQ a;
      a.q = *(const uint4*)&hbuf[s][col * 512 + (((kt << 5) + (quad << 3)) ^ ((col & 7) << 3))];
      acc0 = __builtin_amdgcn_mfma_f32_16x16x32_bf16(u0[kt].v, a.v, acc0, 0, 0, 0);
      acc1 = __builtin_amdgcn_mfma_f32_16x16x32_bf16(u1[kt].v, a.v, acc1, 0, 0, 0);
    }

    const float x0 = xin_s[s][2 * col], x1 = xin_s[s][2 * col + 1];
    unsigned short us[8];
    #pragma unroll
    for (int i = 0; i < 2; i++)
      #pragma unroll
      for (int r = 0; r < 4; r++){
        float zz = (i ? acc1[r] : acc0[r])
                 + fmaf(x0, win0[i*4+r], fmaf(x1, win1[i*4+r], bcv[i*4+r]));
        float e  = __expf(2.0f * zz);
        float th = 1.0f - 2.0f / (e + 1.0f);
        h[i*4+r] = 0.9f * h[i*4+r] + 0.1f * th;
        us[i*4+r] = f2bf(h[i*4+r]);
      }
    own[0] = (unsigned long long)us[0] | ((unsigned long long)us[1] << 16)
           | ((unsigned long long)us[2] << 32) | ((unsigned long long)us[3] << 48);
    own[1] = (unsigned long long)us[4] | ((unsigned long long)us[5] << 16)
           | ((unsigned long long)us[6] << 32) | ((unsigned long long)us[7] << 48);

    if (t < 511){
      const int ns = (t + 1) & 1;
      #pragma unroll
      for (int i = 0; i < 2; i++){
        int n = nbase + i * 16 + (quad << 2);
        unsigned long long old = __hip_atomic_exchange(
            &xm[(ns << 11) + (col << 7) + (n >> 2)], own[i],
            __ATOMIC_RELAXED, __HIP_MEMORY_SCOPE_AGENT);
        asm volatile("" :: "v"(old));   // keep return alive: ack == performed at LLC
      }
      asm volatile("s_waitcnt vmcnt(0)" ::: "memory");  // this wave's sends performed
      __syncthreads();                                  // S3: all waves' sends performed
      if (tid == 0)
        __hip_atomic_store(&flg_my[t], 1, __ATOMIC_RELAXED, __HIP_MEMORY_SCOPE_AGENT);
    }

    #pragma unroll
    for (int i = 0; i < 2; i++)
      *(float4*)&hidden[((size_t)(g16 + col) * 512 + t) * 512 + nbase + i * 16 + (quad << 2)] =
          (float4){h[i*4+0], h[i*4+1], h[i*4+2], h[i*4+3]};
  }
}

// outputs = hidden @ W_out^T : 1024 WGs x 8 waves; WG tile 128M x 512N.
__global__ __launch_bounds__(512, 2)
void out_gemm(const float* __restrict__ hidden, const uint4* __restrict__ wofrag,
              float* __restrict__ outp){
  const int tid  = threadIdx.x;
  const int w    = tid >> 6;
  const int lane = tid & 63;
  const int col  = lane & 15;
  const int quad = lane >> 4;
  const int ms   = w >> 1;
  const int nh   = w & 1;
  const int m0   = blockIdx.x << 7;

  __shared__ unsigned short albf[128 * 32];  // swizzled bf16 A-tile

  f32x4 acc[2][16];
  #pragma unroll
  for (int mt = 0; mt < 2; mt++)
    #pragma unroll
    for (int nt = 0; nt < 16; nt++) acc[mt][nt] = (f32x4){0.f, 0.f, 0.f, 0.f};

  for (int kt = 0; kt < 16; kt++){
    #pragma unroll
    for (int i = 0; i < 2; i++){
      int r  = (tid >> 3) + (i << 6);
      int c4 = (tid & 7) << 2;
      float4 v = *(const float4*)&hidden[(m0 + r) * 512 + (kt << 5) + c4];
      unsigned lo = f2bf(v.x) | ((unsigned)f2bf(v.y) << 16);
      unsigned hi = f2bf(v.z) | ((unsigned)f2bf(v.w) << 16);
      int byteoff = (r << 6) + ((c4 << 1) ^ (((r >> 1) & 3) << 4));
      *(uint2*)((char*)albf + byteoff) = (uint2){lo, hi};
    }
    __syncthreads();

    bf16x8 af[2];
    #pragma unroll
    for (int mt = 0; mt < 2; mt++){
      int rl = (ms << 5) + (mt << 4) + col;
      int byteoff = (rl << 6) + ((quad << 4) ^ (((rl >> 1) & 3) << 4));
      af[mt] = *(const bf16x8*)((const char*)albf + byteoff);
    }

    #pragma unroll
    for (int nt = 0; nt < 16; nt++){
      UQ u; u.q = wofrag[((((nh << 4) + nt) << 4) + kt) * 64 + lane];
      acc[0][nt] = __builtin_amdgcn_mfma_f32_16x16x32_bf16(af[0], u.v, acc[0][nt], 0, 0, 0);
      acc[1][nt] = __builtin_amdgcn_mfma_f32_16x16x32_bf16(af[1], u.v, acc[1][nt], 0, 0, 0);
    }
    __syncthreads();
  }

  #pragma unroll
  for (int mt = 0; mt < 2; mt++)
    #pragma unroll
    for (int nt = 0; nt < 16; nt++)
      #pragma unroll
      for (int r = 0; r < 4; r++)
        outp[(m0 + (ms << 5) + (mt << 4) + (quad << 2) + r) * 512
             + (nh << 8) + (nt << 4) + col] = acc[mt][nt][r];
}

extern "C" void kernel_launch(void* const* d_in, const int* in_sizes, int n_in,
                              void* d_out, int out_size, void* d_ws, size_t ws_size,
                              hipStream_t stream){
  const float* inputs  = (const float*)d_in[0];  // (256,512,2)
  const float* initc   = (const float*)d_in[1];  // (256,512)
  const float* W_in    = (const float*)d_in[2];  // (512,2)
  const float* b_in    = (const float*)d_in[3];  // (512)
  const float* W_rec   = (const float*)d_in[4];  // (512,512)
  const float* b_rec   = (const float*)d_in[5];  // (512)
  const float* W_out   = (const float*)d_in[6];  // (512,512)
  const float* W_hi    = (const float*)d_in[7];  // (512,512)

  float* hidden  = (float*)d_out;                 // 256*512*512
  float* outputs = hidden + (size_t)67108864;     // second half

  char* ws = (char*)d_ws;
  uint4*          wrec_f = (uint4*)ws;                           // 512 KB
  uint4*          wout_f = (uint4*)(ws + (512 << 10));           // 512 KB
  float*          h0     = (float*)(ws + (1024 << 10));          // 512 KB
  unsigned short* hb0    = (unsigned short*)(ws + (1536 << 10)); // 256 KB
  unsigned short* xbuf   = (unsigned short*)(ws + (1792 << 10)); // 512 KB (16 x 2slots x 16x512)
  int*            flags  = (int*)(ws + (2304 << 10));            // 64 KB (2 x 16 x 512)

  zero_flags<<<64, 256, 0, stream>>>(flags);
  pack_kernel<<<64, 512, 0, stream>>>(W_rec, wrec_f);
  pack_kernel<<<64, 512, 0, stream>>>(W_out, wout_f);
  h0_kernel<<<256, 512, 0, stream>>>(initc, W_hi, h0, hb0);
  rnn_kernel<<<32, 512, 0, stream>>>(inputs, W_in, b_in, b_rec, wrec_f, h0, hb0,
                                     xbuf, flags, hidden);
  out_gemm<<<1024, 512, 0, stream>>>(hidden, wout_f, outputs);
}